// Round 17
// baseline (183.913 us; speedup 1.0000x reference)
//
#include <hip/hip_runtime.h>

// Problem constants: B=4, L=1024, D=512, N=16, OUT=512, NL=2
#define BQ 4
#define LQ 1024
#define DQ 512
#define NQ 16
#define MQ (BQ*LQ)      // 4096 rows (b,l flattened)
#define CHUNK 16
#define NCH (LQ/CHUNK)  // 64 chunks
#define KQ 512
#define NFUSE 576       // 512 dt + 16 B + 16 C + 32 pad

typedef __bf16  bf16x8  __attribute__((ext_vector_type(8)));
typedef float   floatx4 __attribute__((ext_vector_type(4)));

__device__ __forceinline__ float softplus_f(float x) {
    return (x > 20.0f) ? x : log1pf(__expf(x));
}
__device__ __forceinline__ unsigned short f2b(float f) {
    union { float f; unsigned u; } x; x.f = f;
    unsigned r = x.u + 0x7fffu + ((x.u >> 16) & 1u);
    return (unsigned short)(r >> 16);
}
__device__ __forceinline__ float b2f(unsigned short u) {
    union { unsigned u; float f; } x; x.u = (unsigned)u << 16;
    return x.f;
}
__device__ __forceinline__ void load_lds16(const void* g, void* l) {
    __builtin_amdgcn_global_load_lds(
        (const __attribute__((address_space(1))) unsigned int*)g,
        (__attribute__((address_space(3))) unsigned int*)l, 16, 0, 0);
}

// ===========================================================================
// Wave-autonomous barrier-free MFMA GEMM core (validated on gemm_final, r16;
// beat the barrier core head-to-head). Each wave: private 16 KB LDS slice
// (4 buffers x 4 KB), BK=32, stages its own 32x32 A/B panels, NO
// __syncthreads. ds_reads gated by manual s_waitcnt vmcnt(12) = wait only
// for loads issued 3 iters ago (prefetch depth 3). sched_barrier(0) pins the
// wait->read order. Entry vmcnt(0) drain makes in-loop FIFO counting exact;
// stray compiler-interleaved VM loads only make waits more conservative.
// Produces acc[2][2] = 32x32 wave tile at (gA rows, gB rows).
// ===========================================================================
__device__ __forceinline__ void wp_stage(
    const unsigned short* gA, const unsigned short* gB,
    unsigned short* buf, int kt, int row16, int gsrc)
{
    load_lds16(gA + (size_t)row16        * KQ + kt + gsrc * 8, buf);
    load_lds16(gA + (size_t)(16 + row16) * KQ + kt + gsrc * 8, buf + 512);
    load_lds16(gB + (size_t)row16        * KQ + kt + gsrc * 8, buf + 1024);
    load_lds16(gB + (size_t)(16 + row16) * KQ + kt + gsrc * 8, buf + 1536);
}

__device__ __forceinline__ void wp_core(
    const unsigned short* gA, const unsigned short* gB,
    unsigned short* my,     // this wave's 16 KB LDS slice
    int lane, floatx4 acc[2][2])
{
    const int r15 = lane & 15, q = lane >> 4;
    const int row16 = lane >> 2, gsrc = (lane & 3) ^ (row16 & 3);
    const int sw = r15 & 3;

    #pragma unroll
    for (int i = 0; i < 2; ++i)
        #pragma unroll
        for (int j = 0; j < 2; ++j) acc[i][j] = (floatx4){0.f,0.f,0.f,0.f};

    __builtin_amdgcn_s_waitcnt(0xF70);       // drain prior VM (exact FIFO base)

    // prologue: stage buffers 0..2 (12 loads outstanding)
    wp_stage(gA, gB, my + 0 * 2048,  0, row16, gsrc);
    wp_stage(gA, gB, my + 1 * 2048, 32, row16, gsrc);
    wp_stage(gA, gB, my + 2 * 2048, 64, row16, gsrc);

    #pragma unroll
    for (int i = 0; i < 16; ++i) {
        if (i < 13)
            wp_stage(gA, gB, my + ((i + 3) & 3) * 2048, (i + 3) * 32, row16, gsrc);
        if (i <= 12)      __builtin_amdgcn_s_waitcnt(0xF70 | 12);
        else if (i == 13) __builtin_amdgcn_s_waitcnt(0xF70 | 8);
        else if (i == 14) __builtin_amdgcn_s_waitcnt(0xF70 | 4);
        else              __builtin_amdgcn_s_waitcnt(0xF70);
        __builtin_amdgcn_sched_barrier(0);
        const unsigned short* bp_ = my + (i & 3) * 2048;
        bf16x8 af0 = *(const bf16x8*)(bp_ +        (      r15) * 32 + (q ^ sw) * 8);
        bf16x8 af1 = *(const bf16x8*)(bp_ +        (16 +  r15) * 32 + (q ^ sw) * 8);
        bf16x8 bf0 = *(const bf16x8*)(bp_ + 1024 + (      r15) * 32 + (q ^ sw) * 8);
        bf16x8 bf1 = *(const bf16x8*)(bp_ + 1024 + (16 +  r15) * 32 + (q ^ sw) * 8);
        acc[0][0] = __builtin_amdgcn_mfma_f32_16x16x32_bf16(af0, bf0, acc[0][0], 0,0,0);
        acc[1][0] = __builtin_amdgcn_mfma_f32_16x16x32_bf16(af1, bf0, acc[1][0], 0,0,0);
        acc[0][1] = __builtin_amdgcn_mfma_f32_16x16x32_bf16(af0, bf1, acc[0][1], 0,0,0);
        acc[1][1] = __builtin_amdgcn_mfma_f32_16x16x32_bf16(af1, bf1, acc[1][1], 0,0,0);
    }
}

// fused-epilogue writer: cols<512 -> softplus->bf16 dt, <528 -> Bm, <544 -> Cm
__device__ __forceinline__ void write_fused(
    floatx4 acc[2][2], int bm, int bn_local,
    const float* __restrict__ bias,    // fused bias vector [576]
    unsigned short* __restrict__ dtb, float* __restrict__ Bm, float* __restrict__ Cm)
{
    const int lane = threadIdx.x & 63, wave = threadIdx.x >> 6;
    const int mw = (wave & 1) * 32, nw = (wave >> 1) * 32;
    const int col0 = lane & 15, rq = lane >> 4;
    #pragma unroll
    for (int nt = 0; nt < 2; ++nt) {
        int nb = bn_local + nw + nt * 16;
        int n  = nb + col0;
        if (nb >= 544) continue;
        float bv = bias[n];
        #pragma unroll
        for (int mt = 0; mt < 2; ++mt)
            #pragma unroll
            for (int r = 0; r < 4; ++r) {
                int m = bm + mw + mt * 16 + rq * 4 + r;
                float v = acc[mt][nt][r] + bv;
                if (nb < 512)      dtb[(size_t)m * DQ + n] = f2b(softplus_f(v));
                else if (nb < 528) Bm[(size_t)m * NQ + (n - 512)] = v;
                else               Cm[(size_t)m * NQ + (n - 528)] = v;
            }
    }
}

// ---------------------------------------------------------------------------
// MERGED dispatch: layer-0 projections GEMM + weight/bias composition.
//  [0,576):   fused0 tiles: dtb0/Bm0/Cm0 = fused(y16 @ Wf0 + bfused0)
//  [576,648): Wcomb1[576][512]    = Wf1_t @ (Wt=Wlin0_o)   bf16
//  [648,712): Wdec_comb[512][512] = Wdec_t @ (Wt=Wlin1_o)  bf16
//  [712,730): bcomb1 dots; [730,746): bdec_comb dots
// All GEMM tiles use the wave-autonomous wp_core (64 KB LDS, 4 waves).
// ---------------------------------------------------------------------------
__global__ __launch_bounds__(256) void gemm_f0_compose(
    const unsigned short* __restrict__ y16,
    const unsigned short* __restrict__ Wf0, const float* __restrict__ bfused0,
    unsigned short* __restrict__ dtb0, float* __restrict__ Bm0, float* __restrict__ Cm0,
    const unsigned short* __restrict__ Wf1_t, const unsigned short* __restrict__ Wlin0_o,
    const unsigned short* __restrict__ Wdec_t, const unsigned short* __restrict__ Wlin1_o,
    const float* __restrict__ blin, const float* __restrict__ bdt,
    const float* __restrict__ bB, const float* __restrict__ bC,
    const float* __restrict__ bdec,
    unsigned short* __restrict__ Wcomb1, unsigned short* __restrict__ Wdec_comb,
    float* __restrict__ bcomb1, float* __restrict__ bdec_comb)
{
    __shared__ __align__(16) unsigned short WP[32768];   // 64 KB, wave-sliced
    const int bid = blockIdx.x, tid = threadIdx.x;
    const int lane = tid & 63, wave = tid >> 6;
    const int mw = (wave & 1) * 32, nw = (wave >> 1) * 32;
    unsigned short* my = WP + wave * 8192;

    if (bid < 576) {
        const int bm = (bid & 63) * 64, bn = (bid >> 6) * 64;
        floatx4 acc[2][2];
        wp_core(y16 + (size_t)(bm + mw) * KQ, Wf0 + (size_t)(bn + nw) * KQ,
                my, lane, acc);
        write_fused(acc, bm, bn, bfused0, dtb0, Bm0, Cm0);
    } else if (bid < 712) {
        const unsigned short *Abf, *Wt; unsigned short* dst;
        int bm, bn;
        if (bid < 648) { int q = bid - 576; Abf = Wf1_t;  Wt = Wlin0_o; dst = Wcomb1;
                         bm = (q / 8) * 64; bn = (q % 8) * 64; }
        else           { int q = bid - 648; Abf = Wdec_t; Wt = Wlin1_o; dst = Wdec_comb;
                         bm = (q / 8) * 64; bn = (q % 8) * 64; }
        floatx4 acc[2][2];
        wp_core(Abf + (size_t)(bm + mw) * KQ, Wt + (size_t)(bn + nw) * KQ,
                my, lane, acc);
        const int col0 = lane & 15, rq = lane >> 4;
        #pragma unroll
        for (int nt = 0; nt < 2; ++nt) {
            int n = bn + nw + nt * 16 + col0;
            #pragma unroll
            for (int mt = 0; mt < 2; ++mt)
                #pragma unroll
                for (int r = 0; r < 4; ++r) {
                    int m = bm + mw + mt * 16 + rq * 4 + r;
                    dst[(size_t)m * KQ + n] = f2b(acc[mt][nt][r]);
                }
        }
    } else {
        // bias dots: 32 outputs/block; 8 lanes per output, 64 elems each
        const int within = tid >> 3, part = tid & 7;
        float acc = 0.f;
        if (bid < 730) {
            int n = (bid - 712) * 32 + within;        // n in [0,576)
            const unsigned short* wrow = Wf1_t + (size_t)n * KQ + part * 64;
            const float* bl = blin;                   // blin0
            #pragma unroll 8
            for (int j = 0; j < 64; ++j)
                acc = fmaf(bl[part * 64 + j], b2f(wrow[j]), acc);
            acc += __shfl_xor(acc, 1);
            acc += __shfl_xor(acc, 2);
            acc += __shfl_xor(acc, 4);
            if (part == 0) {
                float base;
                if (n < 512)      base = bdt[DQ + n];        // layer-1 bdt
                else if (n < 528) base = bB[NQ + (n - 512)];
                else if (n < 544) base = bC[NQ + (n - 528)];
                else              base = 0.f;
                bcomb1[n] = acc + base;
            }
        } else {
            int n = (bid - 730) * 32 + within;        // n in [0,512)
            const unsigned short* wrow = Wdec_t + (size_t)n * KQ + part * 64;
            const float* bl = blin + DQ;              // blin1
            #pragma unroll 8
            for (int j = 0; j < 64; ++j)
                acc = fmaf(bl[part * 64 + j], b2f(wrow[j]), acc);
            acc += __shfl_xor(acc, 1);
            acc += __shfl_xor(acc, 2);
            acc += __shfl_xor(acc, 4);
            if (part == 0) bdec_comb[n] = acc + bdec[n];
        }
    }
}

// ---------------------------------------------------------------------------
// PAIR dispatch: input yact0. grid (64, 17). wp_core everywhere.
//  tiles 0-7  (Wt_lin0): y16b = bf16(yact0@Wlin0 + blin0)
//  tiles 8-16 (Wcomb1):  dtb1/Bm1/Cm1 = fused(yact0@Wcomb1 + bcomb1)
// ---------------------------------------------------------------------------
__global__ __launch_bounds__(256) void gemm_pair(
    const unsigned short* __restrict__ Abf,
    const unsigned short* __restrict__ Wt_lin0,
    const unsigned short* __restrict__ Wcomb1,
    const float* __restrict__ blin0, const float* __restrict__ bcomb1,
    unsigned short* __restrict__ y16b,
    unsigned short* __restrict__ dtb1, float* __restrict__ Bm1, float* __restrict__ Cm1)
{
    __shared__ __align__(16) unsigned short WP[32768];   // 64 KB, wave-sliced
    const int bm = blockIdx.x * 64;
    const int tile = blockIdx.y;
    const int lane = threadIdx.x & 63, wave = threadIdx.x >> 6;
    const int mw = (wave & 1) * 32, nw = (wave >> 1) * 32;
    unsigned short* my = WP + wave * 8192;
    floatx4 acc[2][2];
    if (tile < 8) {
        const int bn = tile * 64;
        wp_core(Abf + (size_t)(bm + mw) * KQ, Wt_lin0 + (size_t)(bn + nw) * KQ,
                my, lane, acc);
        const int col0 = lane & 15, rq = lane >> 4;
        #pragma unroll
        for (int nt = 0; nt < 2; ++nt) {
            int n = bn + nw + nt * 16 + col0;
            float bv = blin0[n];
            #pragma unroll
            for (int mt = 0; mt < 2; ++mt)
                #pragma unroll
                for (int r = 0; r < 4; ++r) {
                    int m = bm + mw + mt * 16 + rq * 4 + r;
                    y16b[(size_t)m * DQ + n] = f2b(acc[mt][nt][r] + bv);
                }
        }
    } else {
        const int bn = (tile - 8) * 64;
        wp_core(Abf + (size_t)(bm + mw) * KQ, Wcomb1 + (size_t)(bn + nw) * KQ,
                my, lane, acc);
        write_fused(acc, bm, bn, bcomb1, dtb1, Bm1, Cm1);
    }
}

// ---------------------------------------------------------------------------
// FINAL: out(fp32) = yact1 @ Wdec_comb + bdec_comb. grid (64, 8). wp_core.
// ---------------------------------------------------------------------------
__global__ __launch_bounds__(256) void gemm_final(
    const unsigned short* __restrict__ Abf,
    const unsigned short* __restrict__ Wt,   // Wdec_comb [512][512]
    const float* __restrict__ bias,          // bdec_comb [512]
    float* __restrict__ out)
{
    __shared__ __align__(16) unsigned short WP[32768];   // 64 KB, wave-sliced
    const int lane = threadIdx.x & 63, wave = threadIdx.x >> 6;
    const int mw = (wave & 1) * 32, nw = (wave >> 1) * 32;
    const int bm = blockIdx.x * 64 + mw, bn = blockIdx.y * 64 + nw;
    unsigned short* my = WP + wave * 8192;
    floatx4 acc[2][2];
    wp_core(Abf + (size_t)bm * KQ, Wt + (size_t)bn * KQ, my, lane, acc);
    const int r15 = lane & 15, q = lane >> 4;
    float bv0 = bias[bn + r15];
    float bv1 = bias[bn + 16 + r15];
    #pragma unroll
    for (int r = 0; r < 4; ++r) {
        int m0 = bm + q * 4 + r, m1 = bm + 16 + q * 4 + r;
        out[(size_t)m0 * DQ + bn + r15]      = acc[0][0][r] + bv0;
        out[(size_t)m1 * DQ + bn + r15]      = acc[1][0][r] + bv0;
        out[(size_t)m0 * DQ + bn + 16 + r15] = acc[0][1][r] + bv1;
        out[(size_t)m1 * DQ + bn + 16 + r15] = acc[1][1][r] + bv1;
    }
}

// ---------------------------------------------------------------------------
// PREP (1 dispatch):
//  [0,1024):    transpose+cast 4 mats, 256 tiles of 32x32 each
//  [1024,1536): plain cast Wlin0_o, Wlin1_o
//  [1536,1664): pack WB/WC into Wf{0,1}_t rows 512..575
//  [1664,3712): cast x -> y16
//  [3712,3715): bfused0 = [bdt0 | bB0 | bC0 | zeros]
// ---------------------------------------------------------------------------
__global__ __launch_bounds__(256) void prep_all(
    const float* __restrict__ Wdt, const float* __restrict__ Wlin,
    const float* __restrict__ Wdec,
    const float* __restrict__ WB, const float* __restrict__ WC,
    const float* __restrict__ x,
    const float* __restrict__ bdt, const float* __restrict__ bB,
    const float* __restrict__ bC,
    unsigned short* __restrict__ Wf0, unsigned short* __restrict__ Wf1,
    unsigned short* __restrict__ Wt_lin0, unsigned short* __restrict__ Wdec_t,
    unsigned short* __restrict__ Wlin0_o, unsigned short* __restrict__ Wlin1_o,
    unsigned short* __restrict__ y16, float* __restrict__ bfused0)
{
    const int bid = blockIdx.x, tid = threadIdx.x;
    if (bid < 1024) {
        __shared__ float tile[32][33];
        int mat = bid >> 8, t = bid & 255;
        const float* src; unsigned short* dst;
        switch (mat) {
            case 0:  src = Wdt;                  dst = Wf0;     break;
            case 1:  src = Wdt + (size_t)KQ*KQ;  dst = Wf1;     break;
            case 2:  src = Wlin;                 dst = Wt_lin0; break;
            default: src = Wdec;                 dst = Wdec_t;  break;
        }
        int bx = (t & 15) * 32, by = (t >> 4) * 32;
        int tx = tid & 31, ty = tid >> 5;
        #pragma unroll
        for (int i = 0; i < 32; i += 8)
            tile[ty + i][tx] = src[(size_t)(bx + ty + i) * KQ + by + tx];
        __syncthreads();
        #pragma unroll
        for (int i = 0; i < 32; i += 8)
            dst[(size_t)(by + ty + i) * KQ + bx + tx] = f2b(tile[tx][ty + i]);
    } else if (bid < 1536) {
        int q = bid - 1024;                    // 512 blocks, 2 mats
        const float* src = (q < 256) ? Wlin : Wlin + (size_t)KQ*KQ;
        unsigned short* dst = (q < 256) ? Wlin0_o : Wlin1_o;
        size_t i = ((size_t)(q & 255) * 256 + tid) * 4;
        float4 v = *(const float4*)(src + i);
        ushort4 o;
        o.x = f2b(v.x); o.y = f2b(v.y); o.z = f2b(v.z); o.w = f2b(v.w);
        *(ushort4*)(dst + i) = o;
    } else if (bid < 1664) {
        int job = bid - 1536;
        int layer = job >> 6, r = job & 63;
        unsigned short* dst = (layer ? Wf1 : Wf0) + (size_t)(512 + r) * KQ;
        const float* src = nullptr;
        int n = 0;
        if (r < 16)      { src = WB + (size_t)layer * DQ * NQ; n = r; }
        else if (r < 32) { src = WC + (size_t)layer * DQ * NQ; n = r - 16; }
        for (int k = tid; k < KQ; k += 256)
            dst[k] = src ? f2b(src[(size_t)k * NQ + n]) : (unsigned short)0;
    } else if (bid < 3712) {
        size_t i = ((size_t)(bid - 1664) * 256 + tid) * 4;
        float4 v = *(const float4*)(x + i);
        ushort4 o;
        o.x = f2b(v.x); o.y = f2b(v.y); o.z = f2b(v.z); o.w = f2b(v.w);
        *(ushort4*)(y16 + i) = o;
    } else {
        int i = (bid - 3712) * 256 + tid;
        if (i < 512)      bfused0[i] = bdt[i];
        else if (i < 528) bfused0[i] = bB[i - 512];
        else if (i < 544) bfused0[i] = bC[i - 528];
        else if (i < 576) bfused0[i] = 0.f;
    }
}

// ---------------------------------------------------------------------------
// Scan phase 1 (CHUNK=16): per (b,d,chunk) cumulative a-prod + local h.
// Summaries ap/hf stored as BF16. grid = B*NCH*2 = 512 blocks.
// ---------------------------------------------------------------------------
__global__ __launch_bounds__(256) void scan_phase1(
    const unsigned short* __restrict__ dt, const unsigned short* __restrict__ y,
    const float* __restrict__ Bm, const float* __restrict__ A,
    unsigned short* __restrict__ ap, unsigned short* __restrict__ hf)
{
    int idx  = blockIdx.x;
    int dblk = idx & 1;
    int c    = (idx >> 1) & (NCH - 1);
    int b    = idx >> 7;
    int d    = dblk * 256 + threadIdx.x;

    float Ad[NQ];
    const float* Aptr = A + (size_t)d * NQ;
    #pragma unroll
    for (int n = 0; n < NQ; ++n) Ad[n] = Aptr[n];

    float h[NQ], prod[NQ];
    #pragma unroll
    for (int n = 0; n < NQ; ++n) { h[n] = 0.f; prod[n] = 1.f; }

    int t0 = c * CHUNK;
    const unsigned short* dtp = dt + ((size_t)b*LQ + t0) * DQ + d;
    const unsigned short* yp  = y  + ((size_t)b*LQ + t0) * DQ + d;
    const float* bp  = Bm + ((size_t)b*LQ + t0) * NQ;

    #pragma unroll 4
    for (int t = 0; t < CHUNK; ++t) {
        float dtv = b2f(dtp[(size_t)t * DQ]);
        float yv  = b2f(yp[(size_t)t * DQ]);
        float dty = dtv * yv;
        #pragma unroll
        for (int n = 0; n < NQ; ++n) {
            float a = __expf(dtv * Ad[n]);
            prod[n] *= a;
            h[n] = fmaf(a, h[n], dty * bp[t*NQ + n]);
        }
    }
    size_t base = ((size_t)(b*NCH + c) * DQ + d) * NQ;
    #pragma unroll
    for (int n = 0; n < NQ; n += 4) {
        ushort4 pa, ph;
        pa.x = f2b(prod[n]);   pa.y = f2b(prod[n+1]);
        pa.z = f2b(prod[n+2]); pa.w = f2b(prod[n+3]);
        ph.x = f2b(h[n]);   ph.y = f2b(h[n+1]);
        ph.z = f2b(h[n+2]); ph.w = f2b(h[n+3]);
        *(ushort4*)(ap + base + n) = pa;
        *(ushort4*)(hf + base + n) = ph;
    }
}

// ---------------------------------------------------------------------------
// Scan phase 2: scan over NCH=64 chunk summaries (bf16); running h stays
// fp32; h_init stored back as bf16 in place over ap. grid 128 blocks.
// ---------------------------------------------------------------------------
__global__ __launch_bounds__(256) void scan_phase2(
    unsigned short* ap, const unsigned short* __restrict__ hf)
{
    int g = blockIdx.x * 256 + threadIdx.x;   // B*D*N = 32768
    int n = g & (NQ - 1);
    int d = (g >> 4) & (DQ - 1);
    int b = g >> 13;
    const size_t stride = (size_t)DQ * NQ;
    size_t base = ((size_t)b * NCH * DQ + d) * NQ + n;
    float h = 0.f;
    for (int c0 = 0; c0 < NCH; c0 += 8) {
        float a[8], f[8];
        #pragma unroll
        for (int j = 0; j < 8; ++j) {
            size_t idx = base + (size_t)(c0 + j) * stride;
            a[j] = b2f(ap[idx]);
            f[j] = b2f(hf[idx]);
        }
        #pragma unroll
        for (int j = 0; j < 8; ++j) {
            size_t idx = base + (size_t)(c0 + j) * stride;
            ap[idx] = f2b(h);
            h = fmaf(a[j], h, f[j]);
        }
    }
}

// ---------------------------------------------------------------------------
// Scan phase 3: recompute local scan with h_init (bf16), emit bf16 yact.
// ---------------------------------------------------------------------------
__global__ __launch_bounds__(256) void scan_phase3(
    const unsigned short* __restrict__ dt, const unsigned short* __restrict__ y,
    const float* __restrict__ Bm, const float* __restrict__ Cm,
    const float* __restrict__ A, const float* __restrict__ Dsk,
    const unsigned short* __restrict__ hi, unsigned short* __restrict__ yact)
{
    int idx  = blockIdx.x;
    int dblk = idx & 1;
    int c    = (idx >> 1) & (NCH - 1);
    int b    = idx >> 7;
    int d    = dblk * 256 + threadIdx.x;

    float Ad[NQ];
    const float* Aptr = A + (size_t)d * NQ;
    #pragma unroll
    for (int n = 0; n < NQ; ++n) Ad[n] = Aptr[n];

    float h[NQ];
    size_t base = ((size_t)(b*NCH + c) * DQ + d) * NQ;
    #pragma unroll
    for (int n = 0; n < NQ; n += 4) {
        ushort4 v = *(const ushort4*)(hi + base + n);
        h[n] = b2f(v.x); h[n+1] = b2f(v.y); h[n+2] = b2f(v.z); h[n+3] = b2f(v.w);
    }
    float dskip = Dsk[d];

    int t0 = c * CHUNK;
    const unsigned short* dtp = dt + ((size_t)b*LQ + t0) * DQ + d;
    const unsigned short* yp  = y  + ((size_t)b*LQ + t0) * DQ + d;
    const float* bp  = Bm + ((size_t)b*LQ + t0) * NQ;
    const float* cp  = Cm + ((size_t)b*LQ + t0) * NQ;
    unsigned short* op = yact + ((size_t)b*LQ + t0) * DQ + d;

    #pragma unroll 4
    for (int t = 0; t < CHUNK; ++t) {
        float dtv = b2f(dtp[(size_t)t * DQ]);
        float yv  = b2f(yp[(size_t)t * DQ]);
        float dty = dtv * yv;
        float acc = 0.f;
        #pragma unroll
        for (int n = 0; n < NQ; ++n) {
            float a = __expf(dtv * Ad[n]);
            h[n] = fmaf(a, h[n], dty * bp[t*NQ + n]);
            acc = fmaf(h[n], cp[t*NQ + n], acc);
        }
        float v = acc + dskip * yv;
        op[(size_t)t * DQ] = f2b(fmaxf(v, 0.f));
    }
}

// ---------------------------------------------------------------------------
extern "C" void kernel_launch(void* const* d_in, const int* in_sizes, int n_in,
                              void* d_out, int out_size, void* d_ws, size_t ws_size,
                              hipStream_t stream)
{
    const float* x    = (const float*)d_in[0];
    const float* A    = (const float*)d_in[1];
    const float* Dsk  = (const float*)d_in[2];
    const float* WB   = (const float*)d_in[3];
    const float* bB   = (const float*)d_in[4];
    const float* WC   = (const float*)d_in[5];
    const float* bC   = (const float*)d_in[6];
    const float* Wdt  = (const float*)d_in[7];
    const float* bdt  = (const float*)d_in[8];
    const float* Wlin = (const float*)d_in[9];
    const float* blin = (const float*)d_in[10];
    const float* Wdec = (const float*)d_in[11];
    const float* bdec = (const float*)d_in[12];
    float* out = (float*)d_out;

    // workspace layout
    char* cur = (char*)d_ws;
    float* Bm0  = (float*)cur;  cur += (size_t)MQ*NQ*4;
    float* Cm0  = (float*)cur;  cur += (size_t)MQ*NQ*4;
    float* Bm1  = (float*)cur;  cur += (size_t)MQ*NQ*4;
    float* Cm1  = (float*)cur;  cur += (size_t)MQ*NQ*4;
    unsigned short* ap = (unsigned short*)cur; cur += (size_t)BQ*NCH*DQ*NQ*2;  // 4 MB
    unsigned short* hf = (unsigned short*)cur; cur += (size_t)BQ*NCH*DQ*NQ*2;  // 4 MB
    unsigned short* y16    = (unsigned short*)cur; cur += (size_t)MQ*DQ*2;
    unsigned short* y16b   = (unsigned short*)cur; cur += (size_t)MQ*DQ*2;
    unsigned short* dtb0   = (unsigned short*)cur; cur += (size_t)MQ*DQ*2;
    unsigned short* dtb1   = (unsigned short*)cur; cur += (size_t)MQ*DQ*2;
    unsigned short* yact   = (unsigned short*)cur; cur += (size_t)MQ*DQ*2;
    unsigned short* Wf0    = (unsigned short*)cur; cur += (size_t)NFUSE*KQ*2;
    unsigned short* Wf1    = (unsigned short*)cur; cur += (size_t)NFUSE*KQ*2;
    unsigned short* Wt_lin0 = (unsigned short*)cur; cur += (size_t)KQ*KQ*2;
    unsigned short* Wdec_t  = (unsigned short*)cur; cur += (size_t)KQ*KQ*2;
    unsigned short* Wlin0_o = (unsigned short*)cur; cur += (size_t)KQ*KQ*2;
    unsigned short* Wlin1_o = (unsigned short*)cur; cur += (size_t)KQ*KQ*2;
    unsigned short* Wcomb1  = (unsigned short*)cur; cur += (size_t)NFUSE*KQ*2;
    unsigned short* Wdec_comb = (unsigned short*)cur; cur += (size_t)KQ*KQ*2;
    float* bfused0   = (float*)cur;  cur += NFUSE*4;
    float* bcomb1    = (float*)cur;  cur += NFUSE*4;
    float* bdec_comb = (float*)cur;  cur += DQ*4;

    dim3 blk(256);

    // 1) prep (transposes, casts, packs, bfused0)
    prep_all<<<dim3(3715), blk, 0, stream>>>(
        Wdt, Wlin, Wdec, WB, WC, x, bdt, bB, bC,
        Wf0, Wf1, Wt_lin0, Wdec_t, Wlin0_o, Wlin1_o, y16, bfused0);

    // 2) layer-0 projections + weight/bias composition (concurrent)
    gemm_f0_compose<<<dim3(746), blk, 0, stream>>>(
        y16, Wf0, bfused0, dtb0, Bm0, Cm0,
        Wf1, Wlin0_o, Wdec_t, Wlin1_o,
        blin, bdt, bB, bC, bdec,
        Wcomb1, Wdec_comb, bcomb1, bdec_comb);

    // 3) layer-0 scan
    scan_phase1<<<dim3(BQ*NCH*2), blk, 0, stream>>>(dtb0, y16, Bm0, A, ap, hf);
    scan_phase2<<<dim3(BQ*DQ*NQ/256), blk, 0, stream>>>(ap, hf);
    scan_phase3<<<dim3(BQ*NCH*2), blk, 0, stream>>>(
        dtb0, y16, Bm0, Cm0, A, Dsk, ap, yact);

    // 4) pair: y16b = yact@Wlin0+blin0  AND  dt/B/C layer1 via composed weights
    gemm_pair<<<dim3(MQ/64, 17), blk, 0, stream>>>(
        yact, Wt_lin0, Wcomb1, blin, bcomb1, y16b, dtb1, Bm1, Cm1);

    // 5) layer-1 scan
    scan_phase1<<<dim3(BQ*NCH*2), blk, 0, stream>>>(
        dtb1, y16b, Bm1, A + (size_t)DQ*NQ, ap, hf);
    scan_phase2<<<dim3(BQ*DQ*NQ/256), blk, 0, stream>>>(ap, hf);
    scan_phase3<<<dim3(BQ*NCH*2), blk, 0, stream>>>(
        dtb1, y16b, Bm1, Cm1, A + (size_t)DQ*NQ, Dsk + DQ, ap, yact);

    // 6) final: out = yact @ (Wlin1·Wdec) + composed bias (wave-pipelined)
    gemm_final<<<dim3(MQ/64, 8), blk, 0, stream>>>(
        yact, Wdec_comb, bdec_comb, out);
}

// Round 18
// 178.742 us; speedup vs baseline: 1.0289x; 1.0289x over previous
//
#include <hip/hip_runtime.h>

// Problem constants: B=4, L=1024, D=512, N=16, OUT=512, NL=2
#define BQ 4
#define LQ 1024
#define DQ 512
#define NQ 16
#define MQ (BQ*LQ)      // 4096 rows (b,l flattened)
#define CHUNK 16
#define NCH (LQ/CHUNK)  // 64 chunks
#define KQ 512
#define NFUSE 576       // 512 dt + 16 B + 16 C + 32 pad

typedef __bf16  bf16x8  __attribute__((ext_vector_type(8)));
typedef float   floatx4 __attribute__((ext_vector_type(4)));

__device__ __forceinline__ float softplus_f(float x) {
    return (x > 20.0f) ? x : log1pf(__expf(x));
}
__device__ __forceinline__ unsigned short f2b(float f) {
    union { float f; unsigned u; } x; x.f = f;
    unsigned r = x.u + 0x7fffu + ((x.u >> 16) & 1u);
    return (unsigned short)(r >> 16);
}
__device__ __forceinline__ float b2f(unsigned short u) {
    union { unsigned u; float f; } x; x.u = (unsigned)u << 16;
    return x.f;
}
__device__ __forceinline__ void load_lds16(const void* g, void* l) {
    __builtin_amdgcn_global_load_lds(
        (const __attribute__((address_space(1))) unsigned int*)g,
        (__attribute__((address_space(3))) unsigned int*)l, 16, 0, 0);
}

// ===========================================================================
// r12 double-buffered MFMA GEMM core (best measured for the big grids):
// 64x64 tile, BK=64, 4 waves (32x32 each), XOR-16B-swizzled LDS, 1 barrier
// per k-iter, prefetch d=1, per-block K-tile stagger (breaks convoy).
// ===========================================================================
__device__ __forceinline__ void stage_tile(
    const unsigned short* g, unsigned short* lds, int wave, int lane)
{
    const int rsub = lane >> 3;
    const int gsrc = (lane & 7) ^ rsub;      // swizzled source granule
    #pragma unroll
    for (int j = 0; j < 2; ++j) {
        int rbase = wave * 16 + j * 8;
        load_lds16(g + (size_t)(rbase + rsub) * KQ + gsrc * 8,
                   lds + (size_t)rbase * 64);
    }
}

__device__ __forceinline__ void gemm_db_core(
    const unsigned short* __restrict__ Abf,
    const unsigned short* __restrict__ Wt,
    int bm, int bn, int stag,
    unsigned short (*As)[64*64], unsigned short (*Bs)[64*64],
    floatx4 acc[2][2])
{
    const int lane = threadIdx.x & 63, wave = threadIdx.x >> 6;
    const int mw = (wave & 1) * 32, nw = (wave >> 1) * 32;
    const int r15 = lane & 15, q = lane >> 4;
    const int slot0 = q ^ (r15 & 7);

    #pragma unroll
    for (int i = 0; i < 2; ++i)
        #pragma unroll
        for (int j = 0; j < 2; ++j) acc[i][j] = (floatx4){0.f,0.f,0.f,0.f};

    const unsigned short* ga = Abf + (size_t)bm * KQ;
    const unsigned short* gb = Wt  + (size_t)bn * KQ;
    {
        int kt = (stag & 7) * 64;
        stage_tile(ga + kt, As[0], wave, lane);
        stage_tile(gb + kt, Bs[0], wave, lane);
    }

    #pragma unroll
    for (int it = 0; it < 8; ++it) {
        __syncthreads();    // drains loads issued LAST iter
        if (it < 7) {
            int kt = ((it + 1 + stag) & 7) * 64;
            stage_tile(ga + kt, As[(it + 1) & 1], wave, lane);
            stage_tile(gb + kt, Bs[(it + 1) & 1], wave, lane);
        }
        const unsigned short* a = As[it & 1];
        const unsigned short* b = Bs[it & 1];
        #pragma unroll
        for (int ks = 0; ks < 2; ++ks) {
            int slot = slot0 ^ (ks * 4);
            bf16x8 af0 = *(const bf16x8*)&a[(mw      + r15) * 64 + slot * 8];
            bf16x8 af1 = *(const bf16x8*)&a[(mw + 16 + r15) * 64 + slot * 8];
            bf16x8 bf0 = *(const bf16x8*)&b[(nw      + r15) * 64 + slot * 8];
            bf16x8 bf1 = *(const bf16x8*)&b[(nw + 16 + r15) * 64 + slot * 8];
            acc[0][0] = __builtin_amdgcn_mfma_f32_16x16x32_bf16(af0, bf0, acc[0][0], 0,0,0);
            acc[1][0] = __builtin_amdgcn_mfma_f32_16x16x32_bf16(af1, bf0, acc[1][0], 0,0,0);
            acc[0][1] = __builtin_amdgcn_mfma_f32_16x16x32_bf16(af0, bf1, acc[0][1], 0,0,0);
            acc[1][1] = __builtin_amdgcn_mfma_f32_16x16x32_bf16(af1, bf1, acc[1][1], 0,0,0);
        }
    }
}

// fused-epilogue writer: cols<512 -> softplus->bf16 dt, <528 -> Bm, <544 -> Cm
__device__ __forceinline__ void write_fused(
    floatx4 acc[2][2], int bm, int bn_local,
    const float* __restrict__ bias,    // fused bias vector [576]
    unsigned short* __restrict__ dtb, float* __restrict__ Bm, float* __restrict__ Cm)
{
    const int lane = threadIdx.x & 63, wave = threadIdx.x >> 6;
    const int mw = (wave & 1) * 32, nw = (wave >> 1) * 32;
    const int col0 = lane & 15, rq = lane >> 4;
    #pragma unroll
    for (int nt = 0; nt < 2; ++nt) {
        int nb = bn_local + nw + nt * 16;
        int n  = nb + col0;
        if (nb >= 544) continue;
        float bv = bias[n];
        #pragma unroll
        for (int mt = 0; mt < 2; ++mt)
            #pragma unroll
            for (int r = 0; r < 4; ++r) {
                int m = bm + mw + mt * 16 + rq * 4 + r;
                float v = acc[mt][nt][r] + bv;
                if (nb < 512)      dtb[(size_t)m * DQ + n] = f2b(softplus_f(v));
                else if (nb < 528) Bm[(size_t)m * NQ + (n - 512)] = v;
                else               Cm[(size_t)m * NQ + (n - 528)] = v;
            }
    }
}

// ---------------------------------------------------------------------------
// MERGED dispatch: layer-0 projections GEMM + weight/bias composition.
//  [0,576):   fused0 tiles: dtb0/Bm0/Cm0 = fused(y16 @ Wf0 + bfused0)
//  [576,648): Wcomb1[576][512]    = Wf1_t @ (Wt=Wlin0_o)   bf16
//  [648,712): Wdec_comb[512][512] = Wdec_t @ (Wt=Wlin1_o)  bf16
//  [712,730): bcomb1[576]: dot(blin0, Wf1_t[n][:]) + {bdt1|bB1|bC1|0}
//  [730,746): bdec_comb[512]: dot(blin1, Wdec_t[n][:]) + bdec
// ---------------------------------------------------------------------------
__global__ __launch_bounds__(256) void gemm_f0_compose(
    const unsigned short* __restrict__ y16,
    const unsigned short* __restrict__ Wf0, const float* __restrict__ bfused0,
    unsigned short* __restrict__ dtb0, float* __restrict__ Bm0, float* __restrict__ Cm0,
    const unsigned short* __restrict__ Wf1_t, const unsigned short* __restrict__ Wlin0_o,
    const unsigned short* __restrict__ Wdec_t, const unsigned short* __restrict__ Wlin1_o,
    const float* __restrict__ blin, const float* __restrict__ bdt,
    const float* __restrict__ bB, const float* __restrict__ bC,
    const float* __restrict__ bdec,
    unsigned short* __restrict__ Wcomb1, unsigned short* __restrict__ Wdec_comb,
    float* __restrict__ bcomb1, float* __restrict__ bdec_comb)
{
    __shared__ __align__(16) unsigned short As[2][64*64];  // 16 KB
    __shared__ __align__(16) unsigned short Bs[2][64*64];  // 16 KB
    const int bid = blockIdx.x, tid = threadIdx.x;
    if (bid < 576) {
        const int bm = (bid & 63) * 64, bn = (bid >> 6) * 64;
        floatx4 acc[2][2];
        gemm_db_core(y16, Wf0, bm, bn, bid, As, Bs, acc);
        write_fused(acc, bm, bn, bfused0, dtb0, Bm0, Cm0);
    } else if (bid < 712) {
        const unsigned short *Abf, *Wt; unsigned short* dst;
        int bm, bn;
        if (bid < 648) { int q = bid - 576; Abf = Wf1_t;  Wt = Wlin0_o; dst = Wcomb1;
                         bm = (q / 8) * 64; bn = (q % 8) * 64; }
        else           { int q = bid - 648; Abf = Wdec_t; Wt = Wlin1_o; dst = Wdec_comb;
                         bm = (q / 8) * 64; bn = (q % 8) * 64; }
        floatx4 acc[2][2];
        gemm_db_core(Abf, Wt, bm, bn, bid, As, Bs, acc);
        const int lane = tid & 63, wave = tid >> 6;
        const int mw = (wave & 1) * 32, nw = (wave >> 1) * 32;
        const int col0 = lane & 15, rq = lane >> 4;
        #pragma unroll
        for (int nt = 0; nt < 2; ++nt) {
            int n = bn + nw + nt * 16 + col0;
            #pragma unroll
            for (int mt = 0; mt < 2; ++mt)
                #pragma unroll
                for (int r = 0; r < 4; ++r) {
                    int m = bm + mw + mt * 16 + rq * 4 + r;
                    dst[(size_t)m * KQ + n] = f2b(acc[mt][nt][r]);
                }
        }
    } else {
        // bias dots: 32 outputs/block; 8 lanes per output, 64 elems each
        const int within = tid >> 3, part = tid & 7;
        float acc = 0.f;
        if (bid < 730) {
            int n = (bid - 712) * 32 + within;        // n in [0,576)
            const unsigned short* wrow = Wf1_t + (size_t)n * KQ + part * 64;
            const float* bl = blin;                   // blin0
            #pragma unroll 8
            for (int j = 0; j < 64; ++j)
                acc = fmaf(bl[part * 64 + j], b2f(wrow[j]), acc);
            acc += __shfl_xor(acc, 1);
            acc += __shfl_xor(acc, 2);
            acc += __shfl_xor(acc, 4);
            if (part == 0) {
                float base;
                if (n < 512)      base = bdt[DQ + n];        // layer-1 bdt
                else if (n < 528) base = bB[NQ + (n - 512)];
                else if (n < 544) base = bC[NQ + (n - 528)];
                else              base = 0.f;
                bcomb1[n] = acc + base;
            }
        } else {
            int n = (bid - 730) * 32 + within;        // n in [0,512)
            const unsigned short* wrow = Wdec_t + (size_t)n * KQ + part * 64;
            const float* bl = blin + DQ;              // blin1
            #pragma unroll 8
            for (int j = 0; j < 64; ++j)
                acc = fmaf(bl[part * 64 + j], b2f(wrow[j]), acc);
            acc += __shfl_xor(acc, 1);
            acc += __shfl_xor(acc, 2);
            acc += __shfl_xor(acc, 4);
            if (part == 0) bdec_comb[n] = acc + bdec[n];
        }
    }
}

// ---------------------------------------------------------------------------
// PAIR dispatch: input yact0. grid (64, 17). barrier core (best here).
//  tiles 0-7  (Wt_lin0): y16b = bf16(yact0@Wlin0 + blin0)
//  tiles 8-16 (Wcomb1):  dtb1/Bm1/Cm1 = fused(yact0@Wcomb1 + bcomb1)
// ---------------------------------------------------------------------------
__global__ __launch_bounds__(256) void gemm_pair(
    const unsigned short* __restrict__ Abf,
    const unsigned short* __restrict__ Wt_lin0,
    const unsigned short* __restrict__ Wcomb1,
    const float* __restrict__ blin0, const float* __restrict__ bcomb1,
    unsigned short* __restrict__ y16b,
    unsigned short* __restrict__ dtb1, float* __restrict__ Bm1, float* __restrict__ Cm1)
{
    __shared__ __align__(16) unsigned short As[2][64*64];
    __shared__ __align__(16) unsigned short Bs[2][64*64];
    const int bm = blockIdx.x * 64;
    const int tile = blockIdx.y;
    const int stag = blockIdx.x + blockIdx.y;
    floatx4 acc[2][2];
    if (tile < 8) {
        const int bn = tile * 64;
        gemm_db_core(Abf, Wt_lin0, bm, bn, stag, As, Bs, acc);
        const int lane = threadIdx.x & 63, wave = threadIdx.x >> 6;
        const int mw = (wave & 1) * 32, nw = (wave >> 1) * 32;
        const int col0 = lane & 15, rq = lane >> 4;
        #pragma unroll
        for (int nt = 0; nt < 2; ++nt) {
            int n = bn + nw + nt * 16 + col0;
            float bv = blin0[n];
            #pragma unroll
            for (int mt = 0; mt < 2; ++mt)
                #pragma unroll
                for (int r = 0; r < 4; ++r) {
                    int m = bm + mw + mt * 16 + rq * 4 + r;
                    y16b[(size_t)m * DQ + n] = f2b(acc[mt][nt][r] + bv);
                }
        }
    } else {
        const int bn = (tile - 8) * 64;
        gemm_db_core(Abf, Wcomb1, bm, bn, stag, As, Bs, acc);
        write_fused(acc, bm, bn, bcomb1, dtb1, Bm1, Cm1);
    }
}

// ===========================================================================
// FINAL GEMM — wave-autonomous barrier-free pipeline (r16-validated WIN).
// Each wave: private 16 KB LDS slice (4 buffers x 4 KB), BK=32, stages its
// own 32x32 A/B panels, NO __syncthreads. ds_reads gated by manual
// s_waitcnt vmcnt(12) = wait only for loads issued 3 iters ago (depth 3).
// sched_barrier(0) pins wait->read order. Bias preloaded + vm drained before
// the loop so vmcnt arithmetic is exact.
// ===========================================================================
__device__ __forceinline__ void wp_stage(
    const unsigned short* gA, const unsigned short* gB,
    unsigned short* buf, int kt, int row16, int gsrc)
{
    load_lds16(gA + (size_t)row16        * KQ + kt + gsrc * 8, buf);
    load_lds16(gA + (size_t)(16 + row16) * KQ + kt + gsrc * 8, buf + 512);
    load_lds16(gB + (size_t)row16        * KQ + kt + gsrc * 8, buf + 1024);
    load_lds16(gB + (size_t)(16 + row16) * KQ + kt + gsrc * 8, buf + 1536);
}

__global__ __launch_bounds__(256) void gemm_final(
    const unsigned short* __restrict__ Abf,
    const unsigned short* __restrict__ Wt,   // Wdec_comb [512][512]
    const float* __restrict__ bias,          // bdec_comb [512]
    float* __restrict__ out)
{
    __shared__ __align__(16) unsigned short WP[32768];   // 64 KB, wave-sliced
    const int lane = threadIdx.x & 63, wave = threadIdx.x >> 6;
    const int mw = (wave & 1) * 32, nw = (wave >> 1) * 32;
    const int bm = blockIdx.x * 64 + mw, bn = blockIdx.y * 64 + nw;
    unsigned short* my = WP + wave * 8192;   // 16 KB slice
    const unsigned short* gA = Abf + (size_t)bm * KQ;
    const unsigned short* gB = Wt  + (size_t)bn * KQ;
    const int r15 = lane & 15, q = lane >> 4;
    const int row16 = lane >> 2, gsrc = (lane & 3) ^ (row16 & 3);
    const int sw = r15 & 3;

    // preload bias, then drain vm so in-loop vmcnt counting is exact
    float bv0 = bias[bn + r15];
    float bv1 = bias[bn + 16 + r15];
    __builtin_amdgcn_s_waitcnt(0xF70);       // vmcnt(0) only

    floatx4 a00 = {0.f,0.f,0.f,0.f}, a01 = a00, a10 = a00, a11 = a00;

    // prologue: stage buffers 0..2 (12 loads outstanding)
    wp_stage(gA, gB, my + 0 * 2048,  0, row16, gsrc);
    wp_stage(gA, gB, my + 1 * 2048, 32, row16, gsrc);
    wp_stage(gA, gB, my + 2 * 2048, 64, row16, gsrc);

    #pragma unroll
    for (int i = 0; i < 16; ++i) {
        if (i < 13)
            wp_stage(gA, gB, my + ((i + 3) & 3) * 2048, (i + 3) * 32, row16, gsrc);
        // wait until stage(i)'s 4 loads have landed (FIFO vmcnt):
        if (i <= 12)      __builtin_amdgcn_s_waitcnt(0xF70 | 12);
        else if (i == 13) __builtin_amdgcn_s_waitcnt(0xF70 | 8);
        else if (i == 14) __builtin_amdgcn_s_waitcnt(0xF70 | 4);
        else              __builtin_amdgcn_s_waitcnt(0xF70);
        __builtin_amdgcn_sched_barrier(0);
        const unsigned short* bp_ = my + (i & 3) * 2048;
        bf16x8 af0 = *(const bf16x8*)(bp_ +        (      r15) * 32 + (q ^ sw) * 8);
        bf16x8 af1 = *(const bf16x8*)(bp_ +        (16 +  r15) * 32 + (q ^ sw) * 8);
        bf16x8 bf0 = *(const bf16x8*)(bp_ + 1024 + (      r15) * 32 + (q ^ sw) * 8);
        bf16x8 bf1 = *(const bf16x8*)(bp_ + 1024 + (16 +  r15) * 32 + (q ^ sw) * 8);
        a00 = __builtin_amdgcn_mfma_f32_16x16x32_bf16(af0, bf0, a00, 0,0,0);
        a10 = __builtin_amdgcn_mfma_f32_16x16x32_bf16(af1, bf0, a10, 0,0,0);
        a01 = __builtin_amdgcn_mfma_f32_16x16x32_bf16(af0, bf1, a01, 0,0,0);
        a11 = __builtin_amdgcn_mfma_f32_16x16x32_bf16(af1, bf1, a11, 0,0,0);
    }

    // epilogue: C/D layout col=lane&15, row=(lane>>4)*4+reg
    #pragma unroll
    for (int r = 0; r < 4; ++r) {
        int m0 = bm + q * 4 + r, m1 = bm + 16 + q * 4 + r;
        out[(size_t)m0 * DQ + bn + r15]      = a00[r] + bv0;
        out[(size_t)m1 * DQ + bn + r15]      = a10[r] + bv0;
        out[(size_t)m0 * DQ + bn + 16 + r15] = a01[r] + bv1;
        out[(size_t)m1 * DQ + bn + 16 + r15] = a11[r] + bv1;
    }
}

// ---------------------------------------------------------------------------
// PREP (1 dispatch):
//  [0,1024):    transpose+cast 4 mats, 256 tiles of 32x32 each
//  [1024,1536): plain cast Wlin0_o, Wlin1_o
//  [1536,1664): pack WB/WC into Wf{0,1}_t rows 512..575
//  [1664,3712): cast x -> y16
//  [3712,3715): bfused0 = [bdt0 | bB0 | bC0 | zeros]
// ---------------------------------------------------------------------------
__global__ __launch_bounds__(256) void prep_all(
    const float* __restrict__ Wdt, const float* __restrict__ Wlin,
    const float* __restrict__ Wdec,
    const float* __restrict__ WB, const float* __restrict__ WC,
    const float* __restrict__ x,
    const float* __restrict__ bdt, const float* __restrict__ bB,
    const float* __restrict__ bC,
    unsigned short* __restrict__ Wf0, unsigned short* __restrict__ Wf1,
    unsigned short* __restrict__ Wt_lin0, unsigned short* __restrict__ Wdec_t,
    unsigned short* __restrict__ Wlin0_o, unsigned short* __restrict__ Wlin1_o,
    unsigned short* __restrict__ y16, float* __restrict__ bfused0)
{
    const int bid = blockIdx.x, tid = threadIdx.x;
    if (bid < 1024) {
        __shared__ float tile[32][33];
        int mat = bid >> 8, t = bid & 255;
        const float* src; unsigned short* dst;
        switch (mat) {
            case 0:  src = Wdt;                  dst = Wf0;     break;
            case 1:  src = Wdt + (size_t)KQ*KQ;  dst = Wf1;     break;
            case 2:  src = Wlin;                 dst = Wt_lin0; break;
            default: src = Wdec;                 dst = Wdec_t;  break;
        }
        int bx = (t & 15) * 32, by = (t >> 4) * 32;
        int tx = tid & 31, ty = tid >> 5;
        #pragma unroll
        for (int i = 0; i < 32; i += 8)
            tile[ty + i][tx] = src[(size_t)(bx + ty + i) * KQ + by + tx];
        __syncthreads();
        #pragma unroll
        for (int i = 0; i < 32; i += 8)
            dst[(size_t)(by + ty + i) * KQ + bx + tx] = f2b(tile[tx][ty + i]);
    } else if (bid < 1536) {
        int q = bid - 1024;                    // 512 blocks, 2 mats
        const float* src = (q < 256) ? Wlin : Wlin + (size_t)KQ*KQ;
        unsigned short* dst = (q < 256) ? Wlin0_o : Wlin1_o;
        size_t i = ((size_t)(q & 255) * 256 + tid) * 4;
        float4 v = *(const float4*)(src + i);
        ushort4 o;
        o.x = f2b(v.x); o.y = f2b(v.y); o.z = f2b(v.z); o.w = f2b(v.w);
        *(ushort4*)(dst + i) = o;
    } else if (bid < 1664) {
        int job = bid - 1536;
        int layer = job >> 6, r = job & 63;
        unsigned short* dst = (layer ? Wf1 : Wf0) + (size_t)(512 + r) * KQ;
        const float* src = nullptr;
        int n = 0;
        if (r < 16)      { src = WB + (size_t)layer * DQ * NQ; n = r; }
        else if (r < 32) { src = WC + (size_t)layer * DQ * NQ; n = r - 16; }
        for (int k = tid; k < KQ; k += 256)
            dst[k] = src ? f2b(src[(size_t)k * NQ + n]) : (unsigned short)0;
    } else if (bid < 3712) {
        size_t i = ((size_t)(bid - 1664) * 256 + tid) * 4;
        float4 v = *(const float4*)(x + i);
        ushort4 o;
        o.x = f2b(v.x); o.y = f2b(v.y); o.z = f2b(v.z); o.w = f2b(v.w);
        *(ushort4*)(y16 + i) = o;
    } else {
        int i = (bid - 3712) * 256 + tid;
        if (i < 512)      bfused0[i] = bdt[i];
        else if (i < 528) bfused0[i] = bB[i - 512];
        else if (i < 544) bfused0[i] = bC[i - 528];
        else if (i < 576) bfused0[i] = 0.f;
    }
}

// ---------------------------------------------------------------------------
// Scan phase 1 (CHUNK=16): per (b,d,chunk) cumulative a-prod + local h.
// Summaries ap/hf stored as BF16. grid = B*NCH*2 = 512 blocks.
// ---------------------------------------------------------------------------
__global__ __launch_bounds__(256) void scan_phase1(
    const unsigned short* __restrict__ dt, const unsigned short* __restrict__ y,
    const float* __restrict__ Bm, const float* __restrict__ A,
    unsigned short* __restrict__ ap, unsigned short* __restrict__ hf)
{
    int idx  = blockIdx.x;
    int dblk = idx & 1;
    int c    = (idx >> 1) & (NCH - 1);
    int b    = idx >> 7;
    int d    = dblk * 256 + threadIdx.x;

    float Ad[NQ];
    const float* Aptr = A + (size_t)d * NQ;
    #pragma unroll
    for (int n = 0; n < NQ; ++n) Ad[n] = Aptr[n];

    float h[NQ], prod[NQ];
    #pragma unroll
    for (int n = 0; n < NQ; ++n) { h[n] = 0.f; prod[n] = 1.f; }

    int t0 = c * CHUNK;
    const unsigned short* dtp = dt + ((size_t)b*LQ + t0) * DQ + d;
    const unsigned short* yp  = y  + ((size_t)b*LQ + t0) * DQ + d;
    const float* bp  = Bm + ((size_t)b*LQ + t0) * NQ;

    #pragma unroll 4
    for (int t = 0; t < CHUNK; ++t) {
        float dtv = b2f(dtp[(size_t)t * DQ]);
        float yv  = b2f(yp[(size_t)t * DQ]);
        float dty = dtv * yv;
        #pragma unroll
        for (int n = 0; n < NQ; ++n) {
            float a = __expf(dtv * Ad[n]);
            prod[n] *= a;
            h[n] = fmaf(a, h[n], dty * bp[t*NQ + n]);
        }
    }
    size_t base = ((size_t)(b*NCH + c) * DQ + d) * NQ;
    #pragma unroll
    for (int n = 0; n < NQ; n += 4) {
        ushort4 pa, ph;
        pa.x = f2b(prod[n]);   pa.y = f2b(prod[n+1]);
        pa.z = f2b(prod[n+2]); pa.w = f2b(prod[n+3]);
        ph.x = f2b(h[n]);   ph.y = f2b(h[n+1]);
        ph.z = f2b(h[n+2]); ph.w = f2b(h[n+3]);
        *(ushort4*)(ap + base + n) = pa;
        *(ushort4*)(hf + base + n) = ph;
    }
}

// ---------------------------------------------------------------------------
// Scan phase 2: scan over NCH=64 chunk summaries (bf16); running h stays
// fp32; h_init stored back as bf16 in place over ap. grid 128 blocks.
// ---------------------------------------------------------------------------
__global__ __launch_bounds__(256) void scan_phase2(
    unsigned short* ap, const unsigned short* __restrict__ hf)
{
    int g = blockIdx.x * 256 + threadIdx.x;   // B*D*N = 32768
    int n = g & (NQ - 1);
    int d = (g >> 4) & (DQ - 1);
    int b = g >> 13;
    const size_t stride = (size_t)DQ * NQ;
    size_t base = ((size_t)b * NCH * DQ + d) * NQ + n;
    float h = 0.f;
    for (int c0 = 0; c0 < NCH; c0 += 8) {
        float a[8], f[8];
        #pragma unroll
        for (int j = 0; j < 8; ++j) {
            size_t idx = base + (size_t)(c0 + j) * stride;
            a[j] = b2f(ap[idx]);
            f[j] = b2f(hf[idx]);
        }
        #pragma unroll
        for (int j = 0; j < 8; ++j) {
            size_t idx = base + (size_t)(c0 + j) * stride;
            ap[idx] = f2b(h);
            h = fmaf(a[j], h, f[j]);
        }
    }
}

// ---------------------------------------------------------------------------
// Scan phase 3: recompute local scan with h_init (bf16), emit bf16 yact.
// ---------------------------------------------------------------------------
__global__ __launch_bounds__(256) void scan_phase3(
    const unsigned short* __restrict__ dt, const unsigned short* __restrict__ y,
    const float* __restrict__ Bm, const float* __restrict__ Cm,
    const float* __restrict__ A, const float* __restrict__ Dsk,
    const unsigned short* __restrict__ hi, unsigned short* __restrict__ yact)
{
    int idx  = blockIdx.x;
    int dblk = idx & 1;
    int c    = (idx >> 1) & (NCH - 1);
    int b    = idx >> 7;
    int d    = dblk * 256 + threadIdx.x;

    float Ad[NQ];
    const float* Aptr = A + (size_t)d * NQ;
    #pragma unroll
    for (int n = 0; n < NQ; ++n) Ad[n] = Aptr[n];

    float h[NQ];
    size_t base = ((size_t)(b*NCH + c) * DQ + d) * NQ;
    #pragma unroll
    for (int n = 0; n < NQ; n += 4) {
        ushort4 v = *(const ushort4*)(hi + base + n);
        h[n] = b2f(v.x); h[n+1] = b2f(v.y); h[n+2] = b2f(v.z); h[n+3] = b2f(v.w);
    }
    float dskip = Dsk[d];

    int t0 = c * CHUNK;
    const unsigned short* dtp = dt + ((size_t)b*LQ + t0) * DQ + d;
    const unsigned short* yp  = y  + ((size_t)b*LQ + t0) * DQ + d;
    const float* bp  = Bm + ((size_t)b*LQ + t0) * NQ;
    const float* cp  = Cm + ((size_t)b*LQ + t0) * NQ;
    unsigned short* op = yact + ((size_t)b*LQ + t0) * DQ + d;

    #pragma unroll 4
    for (int t = 0; t < CHUNK; ++t) {
        float dtv = b2f(dtp[(size_t)t * DQ]);
        float yv  = b2f(yp[(size_t)t * DQ]);
        float dty = dtv * yv;
        float acc = 0.f;
        #pragma unroll
        for (int n = 0; n < NQ; ++n) {
            float a = __expf(dtv * Ad[n]);
            h[n] = fmaf(a, h[n], dty * bp[t*NQ + n]);
            acc = fmaf(h[n], cp[t*NQ + n], acc);
        }
        float v = acc + dskip * yv;
        op[(size_t)t * DQ] = f2b(fmaxf(v, 0.f));
    }
}

// ---------------------------------------------------------------------------
extern "C" void kernel_launch(void* const* d_in, const int* in_sizes, int n_in,
                              void* d_out, int out_size, void* d_ws, size_t ws_size,
                              hipStream_t stream)
{
    const float* x    = (const float*)d_in[0];
    const float* A    = (const float*)d_in[1];
    const float* Dsk  = (const float*)d_in[2];
    const float* WB   = (const float*)d_in[3];
    const float* bB   = (const float*)d_in[4];
    const float* WC   = (const float*)d_in[5];
    const float* bC   = (const float*)d_in[6];
    const float* Wdt  = (const float*)d_in[7];
    const float* bdt  = (const float*)d_in[8];
    const float* Wlin = (const float*)d_in[9];
    const float* blin = (const float*)d_in[10];
    const float* Wdec = (const float*)d_in[11];
    const float* bdec = (const float*)d_in[12];
    float* out = (float*)d_out;

    // workspace layout
    char* cur = (char*)d_ws;
    float* Bm0  = (float*)cur;  cur += (size_t)MQ*NQ*4;
    float* Cm0  = (float*)cur;  cur += (size_t)MQ*NQ*4;
    float* Bm1  = (float*)cur;  cur += (size_t)MQ*NQ*4;
    float* Cm1  = (float*)cur;  cur += (size_t)MQ*NQ*4;
    unsigned short* ap = (unsigned short*)cur; cur += (size_t)BQ*NCH*DQ*NQ*2;  // 4 MB
    unsigned short* hf = (unsigned short*)cur; cur += (size_t)BQ*NCH*DQ*NQ*2;  // 4 MB
    unsigned short* y16    = (unsigned short*)cur; cur += (size_t)MQ*DQ*2;
    unsigned short* y16b   = (unsigned short*)cur; cur += (size_t)MQ*DQ*2;
    unsigned short* dtb0   = (unsigned short*)cur; cur += (size_t)MQ*DQ*2;
    unsigned short* dtb1   = (unsigned short*)cur; cur += (size_t)MQ*DQ*2;
    unsigned short* yact   = (unsigned short*)cur; cur += (size_t)MQ*DQ*2;
    unsigned short* Wf0    = (unsigned short*)cur; cur += (size_t)NFUSE*KQ*2;
    unsigned short* Wf1    = (unsigned short*)cur; cur += (size_t)NFUSE*KQ*2;
    unsigned short* Wt_lin0 = (unsigned short*)cur; cur += (size_t)KQ*KQ*2;
    unsigned short* Wdec_t  = (unsigned short*)cur; cur += (size_t)KQ*KQ*2;
    unsigned short* Wlin0_o = (unsigned short*)cur; cur += (size_t)KQ*KQ*2;
    unsigned short* Wlin1_o = (unsigned short*)cur; cur += (size_t)KQ*KQ*2;
    unsigned short* Wcomb1  = (unsigned short*)cur; cur += (size_t)NFUSE*KQ*2;
    unsigned short* Wdec_comb = (unsigned short*)cur; cur += (size_t)KQ*KQ*2;
    float* bfused0   = (float*)cur;  cur += NFUSE*4;
    float* bcomb1    = (float*)cur;  cur += NFUSE*4;
    float* bdec_comb = (float*)cur;  cur += DQ*4;

    dim3 blk(256);

    // 1) prep (transposes, casts, packs, bfused0)
    prep_all<<<dim3(3715), blk, 0, stream>>>(
        Wdt, Wlin, Wdec, WB, WC, x, bdt, bB, bC,
        Wf0, Wf1, Wt_lin0, Wdec_t, Wlin0_o, Wlin1_o, y16, bfused0);

    // 2) layer-0 projections + weight/bias composition (concurrent)
    gemm_f0_compose<<<dim3(746), blk, 0, stream>>>(
        y16, Wf0, bfused0, dtb0, Bm0, Cm0,
        Wf1, Wlin0_o, Wdec_t, Wlin1_o,
        blin, bdt, bB, bC, bdec,
        Wcomb1, Wdec_comb, bcomb1, bdec_comb);

    // 3) layer-0 scan
    scan_phase1<<<dim3(BQ*NCH*2), blk, 0, stream>>>(dtb0, y16, Bm0, A, ap, hf);
    scan_phase2<<<dim3(BQ*DQ*NQ/256), blk, 0, stream>>>(ap, hf);
    scan_phase3<<<dim3(BQ*NCH*2), blk, 0, stream>>>(
        dtb0, y16, Bm0, Cm0, A, Dsk, ap, yact);

    // 4) pair: y16b = yact@Wlin0+blin0  AND  dt/B/C layer1 via composed weights
    gemm_pair<<<dim3(MQ/64, 17), blk, 0, stream>>>(
        yact, Wt_lin0, Wcomb1, blin, bcomb1, y16b, dtb1, Bm1, Cm1);

    // 5) layer-1 scan
    scan_phase1<<<dim3(BQ*NCH*2), blk, 0, stream>>>(
        dtb1, y16b, Bm1, A + (size_t)DQ*NQ, ap, hf);
    scan_phase2<<<dim3(BQ*DQ*NQ/256), blk, 0, stream>>>(ap, hf);
    scan_phase3<<<dim3(BQ*NCH*2), blk, 0, stream>>>(
        dtb1, y16b, Bm1, Cm1, A + (size_t)DQ*NQ, Dsk + DQ, ap, yact);

    // 6) final: out = yact @ (Wlin1·Wdec) + composed bias (wave-pipelined)
    gemm_final<<<dim3(MQ/64, 8), blk, 0, stream>>>(
        yact, Wdec_comb, bdec_comb, out);
}